// Round 10
// baseline (215.758 us; speedup 1.0000x reference)
//
#include <hip/hip_runtime.h>
#include <hip/hip_bf16.h>
#include <math.h>

// Problem constants
#define Bsz 2
#define Nseq 2048
#define Edim 1024
#define HQ 16
#define HK 4
#define Dh 64
#define ROWS (Bsz * Nseq)          // 4096
#define QKVW 1536                  // q(1024) | k(256) | v(256)
#define SCL 0.1803368801111244f    // 0.125 * log2(e)  (folded into Wq at prep)

typedef __attribute__((ext_vector_type(8))) short short8;
typedef __attribute__((ext_vector_type(4))) float f32x4;

union S8U { short8 s8; unsigned u[4]; };

__device__ __forceinline__ ushort f2bf_u(float f) {
    union { __hip_bfloat16 h; ushort u; } c;
    c.h = __float2bfloat16(f);
    return c.u;
}
__device__ __forceinline__ unsigned bfpk(float lo, float hi) {
    return ((unsigned)f2bf_u(hi) << 16) | (unsigned)f2bf_u(lo);
}

// async global->LDS, 16B per lane; lds base must be wave-uniform
__device__ __forceinline__ void gld16(const void* g, void* l) {
    __builtin_amdgcn_global_load_lds(
        (const __attribute__((address_space(1))) unsigned*)g,
        (__attribute__((address_space(3))) unsigned*)l, 16, 0, 0);
}

// ---------------- prep: cast x + transpose-cast all weights, one launch ------
// blocks 0..2047: x cast. blocks 2048..4607: weight transpose (Wq pre-scaled).
__global__ __launch_bounds__(256) void prep(const float* __restrict__ x,
                                            const float* __restrict__ Wq,
                                            const float* __restrict__ Wk,
                                            const float* __restrict__ Wv,
                                            const float* __restrict__ Wo,
                                            ushort* __restrict__ xb,
                                            ushort* __restrict__ WqkvT,
                                            ushort* __restrict__ WoT) {
    if (blockIdx.x < 2048) {
        size_t i = ((size_t)blockIdx.x * 256 + threadIdx.x) * 8;
        float4 a = *(const float4*)(x + i);
        float4 c = *(const float4*)(x + i + 4);
        short8 v;
        v[0] = f2bf_u(a.x); v[1] = f2bf_u(a.y); v[2] = f2bf_u(a.z); v[3] = f2bf_u(a.w);
        v[4] = f2bf_u(c.x); v[5] = f2bf_u(c.y); v[6] = f2bf_u(c.z); v[7] = f2bf_u(c.w);
        *(short8*)(xb + i) = v;
        return;
    }
    __shared__ float tle[32][33];
    int bid = blockIdx.x - 2048;
    const float* src; ushort* dst; int N; float sc = 1.0f;
    if (bid < 1024)      { src = Wq; dst = WqkvT;                          N = 1024; sc = SCL; }
    else if (bid < 1280) { src = Wk; dst = WqkvT + (size_t)1024 * 1024;    N = 256;  bid -= 1024; }
    else if (bid < 1536) { src = Wv; dst = WqkvT + (size_t)1280 * 1024;    N = 256;  bid -= 1280; }
    else                 { src = Wo; dst = WoT;                            N = 1024; bid -= 1536; }
    int nj = N >> 5;
    int j0 = (bid % nj) * 32, k0 = (bid / nj) * 32;
    int tx = threadIdx.x & 31, ty = threadIdx.x >> 5;
#pragma unroll
    for (int i = ty; i < 32; i += 8)
        tle[i][tx] = src[(size_t)(k0 + i) * N + j0 + tx];
    __syncthreads();
#pragma unroll
    for (int i = ty; i < 32; i += 8)
        dst[(size_t)(j0 + i) * 1024 + k0 + tx] = f2bf_u(tle[tx][i] * sc);
}

// ---------------- bf16 MFMA GEMM: C[M][N] = A[M][K] @ BT[N][K]^T -------------
// 128x64 tile, BK=64 (nk=16): per-barrier work ~2x load latency -> drain
// amortized. 48KB LDS dbuf -> 3 blocks/CU.
template<int WRITE_BF16>
__global__ __launch_bounds__(256) void gemm_bt(const ushort* __restrict__ A,
                                               const ushort* __restrict__ BT,
                                               void* __restrict__ Cout,
                                               int M, int N, int K) {
    __shared__ __attribute__((aligned(16))) ushort As[2][8][128][8];  // 32KB
    __shared__ __attribute__((aligned(16))) ushort Bs[2][8][64][8];   // 16KB
    const int tid = threadIdx.x;
    const int l = tid & 63, li = l & 15, lg = l >> 4;
    const int w = tid >> 6;
    const int wr = w >> 1, wc = w & 1;
    const int row0 = blockIdx.y * 128, col0 = blockIdx.x * 64;

    f32x4 acc[4][2];
#pragma unroll
    for (int i = 0; i < 4; ++i)
#pragma unroll
        for (int j = 0; j < 2; ++j) {
            acc[i][j][0] = 0.f; acc[i][j][1] = 0.f;
            acc[i][j][2] = 0.f; acc[i][j][3] = 0.f;
        }

    const int nk = K >> 6;

#define G_STAGE(buf, kk)                                                        \
    {                                                                           \
        int k0 = (kk) << 6;                                                     \
        _Pragma("unroll")                                                       \
        for (int i = 0; i < 6; ++i) {                                           \
            int id = w + i * 4;                                                 \
            if (id < 16) {                                                      \
                int g = id >> 1, h = id & 1;                                    \
                gld16(A + (size_t)(row0 + h * 64 + l) * K + k0 + g * 8,         \
                      &As[buf][g][h * 64][0]);                                  \
            } else {                                                            \
                int g = id - 16;                                                \
                gld16(BT + (size_t)(col0 + l) * K + k0 + g * 8,                 \
                      &Bs[buf][g][0][0]);                                       \
            }                                                                   \
        }                                                                       \
    }

    G_STAGE(0, 0);
    __syncthreads();
    int buf = 0;
    for (int kk = 0; kk < nk; ++kk) {
        if (kk + 1 < nk) G_STAGE(buf ^ 1, kk + 1);
#pragma unroll
        for (int ks = 0; ks < 2; ++ks) {
            short8 af[4], bfr[2];
#pragma unroll
            for (int mt = 0; mt < 4; ++mt)
                af[mt] = *(const short8*)&As[buf][ks * 4 + lg][wr * 64 + mt * 16 + li][0];
#pragma unroll
            for (int nt = 0; nt < 2; ++nt)
                bfr[nt] = *(const short8*)&Bs[buf][ks * 4 + lg][wc * 32 + nt * 16 + li][0];
#pragma unroll
            for (int mt = 0; mt < 4; ++mt)
#pragma unroll
                for (int nt = 0; nt < 2; ++nt)
                    acc[mt][nt] = __builtin_amdgcn_mfma_f32_16x16x32_bf16(
                        af[mt], bfr[nt], acc[mt][nt], 0, 0, 0);
        }
        __syncthreads();
        buf ^= 1;
    }
#undef G_STAGE

    if (WRITE_BF16) {
        ushort* C = (ushort*)Cout;
#pragma unroll
        for (int mt = 0; mt < 4; ++mt)
#pragma unroll
            for (int r = 0; r < 4; ++r) {
                int rg = row0 + wr * 64 + mt * 16 + lg * 4 + r;
#pragma unroll
                for (int nt = 0; nt < 2; ++nt)
                    C[(size_t)rg * N + col0 + wc * 32 + nt * 16 + li] =
                        f2bf_u(acc[mt][nt][r]);
            }
    } else {
        float* C = (float*)Cout;
#pragma unroll
        for (int mt = 0; mt < 4; ++mt)
#pragma unroll
            for (int r = 0; r < 4; ++r) {
                int rg = row0 + wr * 64 + mt * 16 + lg * 4 + r;
#pragma unroll
                for (int nt = 0; nt < 2; ++nt)
                    C[(size_t)rg * N + col0 + wc * 32 + nt * 16 + li] =
                        acc[mt][nt][r];
            }
    }
}

// ---------------- flash attention: 128-key pairs per barrier -----------------
// Block handles q-tiles {bx, 31-bx} (17 pairs uniform). Per pair-iteration:
// stage next K-pair (gld16 dbuf) + V-pair (regs), QK^T both tiles, ONE softmax
// over 32 scores (defer-max THR=8, exact), V-write, pack+PV per tile, barrier.
// LDS 72KB -> 2 blocks/CU (= grid). Tail tile fully masked (exact).
__global__ __launch_bounds__(256) void attn_mfma(const ushort* __restrict__ qkv,
                                                 ushort* __restrict__ o) {
    __shared__ __attribute__((aligned(16))) char smem[73728];
    ushort (*Ks)[2][8][64][8] = (ushort (*)[2][8][64][8])smem;          // 2x16KB
    unsigned (*VtD)[2][2048]  = (unsigned (*)[2][2048])(smem + 32768);  // 2x16KB
    ushort (*Ps)[8][16][8]    = (ushort (*)[8][16][8])(smem + 65536);   // 8KB

    const int tid = threadIdx.x;
    const int l = tid & 63, li = l & 15, lg = l >> 4;
    const int w = tid >> 6;
    const int bx = blockIdx.x;                   // 0..15
    const int hq = blockIdx.y, b = blockIdx.z, hk = hq >> 2;

    // V-stage lane mapping: thread owns keys (kp,kp+1) x 8 d's (per tile)
    const int kp = 2 * (tid & 31), d0v = (tid >> 5) * 8;
    const int gv = kp >> 3, prv = (kp & 7) >> 1;

    const ushort* base  = qkv + (size_t)b * Nseq * QKVW;
    const ushort* vbase = base + 1280 + hk * 64 + d0v;     // + row*QKVW
    const int qloc = w * 16 + li;                          // lane's q-row in tile

    for (int hseg = 0; hseg < 2; ++hseg) {
        const int qt = hseg ? (31 - bx) : bx;
        const int r0 = qt * 64;
        const int npair = (qt + 2) >> 1;

        // Q fragments per-lane (pre-scaled by SCL via Wq)
        short8 q8[2];
#pragma unroll
        for (int c = 0; c < 2; ++c)
            q8[c] = *(const short8*)(base + (size_t)(r0 + qloc) * QKVW +
                                     hq * 64 + (c * 4 + lg) * 8);

        // prologue: stage K pair0 via gld16, V pair0 via regs
#pragma unroll
        for (int i = 0; i < 4; ++i) {
            int id = w + i * 4, tile = id >> 3, g = id & 7;
            gld16(base + (size_t)(tile * 64 + l) * QKVW + 1024 + hk * 64 + g * 8,
                  &Ks[0][tile][g][0][0]);
        }
        short8 v0a = *(const short8*)(vbase + (size_t)kp * QKVW);
        short8 v0b = *(const short8*)(vbase + (size_t)(kp + 1) * QKVW);
        short8 v1a = *(const short8*)(vbase + (size_t)(64 + kp) * QKVW);
        short8 v1b = *(const short8*)(vbase + (size_t)(64 + kp + 1) * QKVW);
        __syncthreads();                  // K pair0 in LDS; V regs complete
        {
            S8U ua0, ub0, ua1, ub1;
            ua0.s8 = v0a; ub0.s8 = v0b; ua1.s8 = v1a; ub1.s8 = v1b;
#pragma unroll
            for (int j = 0; j < 4; ++j) {
                VtD[0][0][gv * 256 + (((d0v + 2 * j) * 4 + prv) ^ (gv << 2))] =
                    __builtin_amdgcn_perm(ub0.u[j], ua0.u[j], 0x05040100u);
                VtD[0][0][gv * 256 + (((d0v + 2 * j + 1) * 4 + prv) ^ (gv << 2))] =
                    __builtin_amdgcn_perm(ub0.u[j], ua0.u[j], 0x07060302u);
                VtD[0][1][gv * 256 + (((d0v + 2 * j) * 4 + prv) ^ (gv << 2))] =
                    __builtin_amdgcn_perm(ub1.u[j], ua1.u[j], 0x05040100u);
                VtD[0][1][gv * 256 + (((d0v + 2 * j + 1) * 4 + prv) ^ (gv << 2))] =
                    __builtin_amdgcn_perm(ub1.u[j], ua1.u[j], 0x07060302u);
            }
        }
        __syncthreads();                  // V pair0 visible

        f32x4 oacc[4];
#pragma unroll
        for (int dt = 0; dt < 4; ++dt) {
            oacc[dt][0] = 0.f; oacc[dt][1] = 0.f;
            oacc[dt][2] = 0.f; oacc[dt][3] = 0.f;
        }
        float m = -INFINITY, lsum = 0.f;

        for (int pt = 0; pt < npair; ++pt) {
            const int cur = pt & 1, nxt = cur ^ 1;
            const bool pre = (pt + 1 < npair);
            short8 vn0a, vn0b, vn1a, vn1b;
            if (pre) {                    // issue next pair's loads FIRST
                const int s1 = (pt + 1) * 128;
#pragma unroll
                for (int i = 0; i < 4; ++i) {
                    int id = w + i * 4, tile = id >> 3, g = id & 7;
                    gld16(base + (size_t)(s1 + tile * 64 + l) * QKVW + 1024 + hk * 64 + g * 8,
                          &Ks[nxt][tile][g][0][0]);
                }
                vn0a = *(const short8*)(vbase + (size_t)(s1 + kp) * QKVW);
                vn0b = *(const short8*)(vbase + (size_t)(s1 + kp + 1) * QKVW);
                vn1a = *(const short8*)(vbase + (size_t)(s1 + 64 + kp) * QKVW);
                vn1b = *(const short8*)(vbase + (size_t)(s1 + 64 + kp + 1) * QKVW);
            }

            // QK^T both tiles -> p[32] (masked, exp2-domain scores)
            float p[32];
#pragma unroll
            for (int tt = 0; tt < 2; ++tt) {
                f32x4 s[4];
#pragma unroll
                for (int kb = 0; kb < 4; ++kb) {
                    s[kb][0] = 0.f; s[kb][1] = 0.f; s[kb][2] = 0.f; s[kb][3] = 0.f;
                }
#pragma unroll
                for (int c = 0; c < 2; ++c)
#pragma unroll
                    for (int kb = 0; kb < 4; ++kb) {
                        short8 bk = *(const short8*)&Ks[cur][tt][c * 4 + lg][kb * 16 + li][0];
                        s[kb] = __builtin_amdgcn_mfma_f32_16x16x32_bf16(bk, q8[c], s[kb], 0, 0, 0);
                    }
                const int tglob = pt * 2 + tt;
                const bool diag = (tglob == qt), over = (tglob > qt);
#pragma unroll
                for (int kb = 0; kb < 4; ++kb)
#pragma unroll
                    for (int r = 0; r < 4; ++r) {
                        float sv = s[kb][r];
                        if (over || (diag && (kb * 16 + lg * 4 + r > qloc)))
                            sv = -INFINITY;
                        p[tt * 16 + kb * 4 + r] = sv;
                    }
            }

            // one softmax over 32: max tree + 2 shfl
            float mx = p[0];
#pragma unroll
            for (int i = 1; i < 32; ++i) mx = fmaxf(mx, p[i]);
            mx = fmaxf(mx, __shfl_xor(mx, 16, 64));
            mx = fmaxf(mx, __shfl_xor(mx, 32, 64));

            // defer-max (exact): update offset only on growth > 8
            if (__any(mx - m > 8.0f)) {
                float mn = fmaxf(m, mx);
                float al = exp2f(m - mn);   // first pair: exp2(-inf)=0
                m = mn;
                lsum *= al;
                float alr[4];
#pragma unroll
                for (int r = 0; r < 4; ++r) alr[r] = __shfl(al, lg * 4 + r, 64);
#pragma unroll
                for (int dt = 0; dt < 4; ++dt)
#pragma unroll
                    for (int r = 0; r < 4; ++r) oacc[dt][r] *= alr[r];
            }

            float sum = 0.f;
#pragma unroll
            for (int i = 0; i < 32; ++i) {
                float e = exp2f(p[i] - m);
                p[i] = e;
                sum += e;
            }
            sum += __shfl_xor(sum, 16, 64);
            sum += __shfl_xor(sum, 32, 64);
            lsum += sum;

            // write V(next pair) regs -> LDS (overlapped with softmax above)
            if (pre) {
                S8U ua0, ub0, ua1, ub1;
                ua0.s8 = vn0a; ub0.s8 = vn0b; ua1.s8 = vn1a; ub1.s8 = vn1b;
#pragma unroll
                for (int j = 0; j < 4; ++j) {
                    VtD[nxt][0][gv * 256 + (((d0v + 2 * j) * 4 + prv) ^ (gv << 2))] =
                        __builtin_amdgcn_perm(ub0.u[j], ua0.u[j], 0x05040100u);
                    VtD[nxt][0][gv * 256 + (((d0v + 2 * j + 1) * 4 + prv) ^ (gv << 2))] =
                        __builtin_amdgcn_perm(ub0.u[j], ua0.u[j], 0x07060302u);
                    VtD[nxt][1][gv * 256 + (((d0v + 2 * j) * 4 + prv) ^ (gv << 2))] =
                        __builtin_amdgcn_perm(ub1.u[j], ua1.u[j], 0x05040100u);
                    VtD[nxt][1][gv * 256 + (((d0v + 2 * j + 1) * 4 + prv) ^ (gv << 2))] =
                        __builtin_amdgcn_perm(ub1.u[j], ua1.u[j], 0x07060302u);
                }
            }

            // pack P + PV per tile (same-wave LDS: in-order, no barrier)
#pragma unroll
            for (int tt = 0; tt < 2; ++tt) {
#pragma unroll
                for (int kb = 0; kb < 4; ++kb) {
                    unsigned lo = bfpk(p[tt * 16 + kb * 4 + 0], p[tt * 16 + kb * 4 + 1]);
                    unsigned hi = bfpk(p[tt * 16 + kb * 4 + 2], p[tt * 16 + kb * 4 + 3]);
                    *(unsigned long long*)&Ps[w][2 * kb + (lg >> 1)][li][(lg & 1) * 4] =
                        ((unsigned long long)hi << 32) | (unsigned long long)lo;
                }
#pragma unroll
                for (int c = 0; c < 2; ++c) {
                    short8 pa = *(const short8*)&Ps[w][c * 4 + lg][li][0];
#pragma unroll
                    for (int dt = 0; dt < 4; ++dt) {
                        int g = c * 4 + lg, d = dt * 16 + li;
                        short8 bv = *(const short8*)(&VtD[cur][tt][g * 256 + ((d * 4) ^ (g << 2))]);
                        oacc[dt] = __builtin_amdgcn_mfma_f32_16x16x32_bf16(pa, bv, oacc[dt], 0, 0, 0);
                    }
                }
            }
            __syncthreads();   // drains next-pair gld16 + V writes; cur reads done
        }

        // epilogue: 1/l for q-row lg*4+r from lane lg*4+r
        float linv[4];
#pragma unroll
        for (int r = 0; r < 4; ++r) linv[r] = 1.0f / __shfl(lsum, lg * 4 + r, 64);
#pragma unroll
        for (int r = 0; r < 4; ++r) {
            int rg = b * Nseq + r0 + w * 16 + lg * 4 + r;
#pragma unroll
            for (int dt = 0; dt < 4; ++dt)
                o[(size_t)rg * Edim + hq * 64 + dt * 16 + li] =
                    f2bf_u(oacc[dt][r] * linv[r]);
        }
        // loop's final __syncthreads ordered all LDS reads before next half
    }
}

// ---------------- launch ------------------------------------------------------
extern "C" void kernel_launch(void* const* d_in, const int* in_sizes, int n_in,
                              void* d_out, int out_size, void* d_ws, size_t ws_size,
                              hipStream_t stream) {
    const float* x  = (const float*)d_in[0];
    const float* Wq = (const float*)d_in[1];
    const float* Wk = (const float*)d_in[2];
    const float* Wv = (const float*)d_in[3];
    const float* Wo = (const float*)d_in[4];

    ushort* ws    = (ushort*)d_ws;
    ushort* xb    = ws;                          // 4096x1024
    ushort* WqkvT = xb + (size_t)ROWS * Edim;    // 1536x1024 (rows: WqT|WkT|WvT)
    ushort* WoT   = WqkvT + (size_t)QKVW * Edim; // 1024x1024
    ushort* qkv   = WoT + (size_t)Edim * Edim;   // 4096x1536 bf16
    ushort* at    = qkv + (size_t)ROWS * QKVW;   // 4096x1024 bf16

    prep<<<4608, 256, 0, stream>>>(x, Wq, Wk, Wv, Wo, xb, WqkvT, WoT);

    gemm_bt<1><<<dim3(QKVW / 64, ROWS / 128), 256, 0, stream>>>(
        xb, WqkvT, qkv, ROWS, QKVW, Edim);

    attn_mfma<<<dim3(Nseq / 128, HQ, Bsz), 256, 0, stream>>>(qkv, at);

    gemm_bt<0><<<dim3(Edim / 64, ROWS / 128), 256, 0, stream>>>(
        at, WoT, d_out, ROWS, Edim, Edim);
}

// Round 11
// 206.378 us; speedup vs baseline: 1.0454x; 1.0454x over previous
//
#include <hip/hip_runtime.h>
#include <hip/hip_bf16.h>
#include <math.h>

// Problem constants
#define Bsz 2
#define Nseq 2048
#define Edim 1024
#define HQ 16
#define HK 4
#define Dh 64
#define ROWS (Bsz * Nseq)          // 4096
#define QKVW 1536                  // q(1024) | k(256) | v(256)
#define SCL 0.1803368801111244f    // 0.125 * log2(e)  (folded into Wq at prep)

typedef __attribute__((ext_vector_type(8))) short short8;
typedef __attribute__((ext_vector_type(4))) float f32x4;

union S8U { short8 s8; unsigned u[4]; };

__device__ __forceinline__ ushort f2bf_u(float f) {
    union { __hip_bfloat16 h; ushort u; } c;
    c.h = __float2bfloat16(f);
    return c.u;
}
__device__ __forceinline__ unsigned bfpk(float lo, float hi) {
    return ((unsigned)f2bf_u(hi) << 16) | (unsigned)f2bf_u(lo);
}

// async global->LDS, 16B per lane; lds base must be wave-uniform
__device__ __forceinline__ void gld16(const void* g, void* l) {
    __builtin_amdgcn_global_load_lds(
        (const __attribute__((address_space(1))) unsigned*)g,
        (__attribute__((address_space(3))) unsigned*)l, 16, 0, 0);
}

// ---------------- prep: cast x + transpose-cast all weights, one launch ------
__global__ __launch_bounds__(256) void prep(const float* __restrict__ x,
                                            const float* __restrict__ Wq,
                                            const float* __restrict__ Wk,
                                            const float* __restrict__ Wv,
                                            const float* __restrict__ Wo,
                                            ushort* __restrict__ xb,
                                            ushort* __restrict__ WqkvT,
                                            ushort* __restrict__ WoT) {
    if (blockIdx.x < 2048) {
        size_t i = ((size_t)blockIdx.x * 256 + threadIdx.x) * 8;
        float4 a = *(const float4*)(x + i);
        float4 c = *(const float4*)(x + i + 4);
        short8 v;
        v[0] = f2bf_u(a.x); v[1] = f2bf_u(a.y); v[2] = f2bf_u(a.z); v[3] = f2bf_u(a.w);
        v[4] = f2bf_u(c.x); v[5] = f2bf_u(c.y); v[6] = f2bf_u(c.z); v[7] = f2bf_u(c.w);
        *(short8*)(xb + i) = v;
        return;
    }
    __shared__ float tle[32][33];
    int bid = blockIdx.x - 2048;
    const float* src; ushort* dst; int N; float sc = 1.0f;
    if (bid < 1024)      { src = Wq; dst = WqkvT;                          N = 1024; sc = SCL; }
    else if (bid < 1280) { src = Wk; dst = WqkvT + (size_t)1024 * 1024;    N = 256;  bid -= 1024; }
    else if (bid < 1536) { src = Wv; dst = WqkvT + (size_t)1280 * 1024;    N = 256;  bid -= 1280; }
    else                 { src = Wo; dst = WoT;                            N = 1024; bid -= 1536; }
    int nj = N >> 5;
    int j0 = (bid % nj) * 32, k0 = (bid / nj) * 32;
    int tx = threadIdx.x & 31, ty = threadIdx.x >> 5;
#pragma unroll
    for (int i = ty; i < 32; i += 8)
        tle[i][tx] = src[(size_t)(k0 + i) * N + j0 + tx];
    __syncthreads();
#pragma unroll
    for (int i = ty; i < 32; i += 8)
        dst[(size_t)(j0 + i) * 1024 + k0 + tx] = f2bf_u(tle[tx][i] * sc);
}

// ---------------- bf16 MFMA GEMM: C[M][N] = A[M][K] @ BT[N][K]^T -------------
// 128x128 tile, BK=32 (m97 structure: 16 MFMA : 8 ds_read_b128 = 2:1),
// 32KB LDS dbuf -> 3 blocks/CU. 1-D grid + bijective XCD swizzle (nwg%8==0).
template<int WRITE_BF16>
__global__ __launch_bounds__(256) void gemm_bt(const ushort* __restrict__ A,
                                               const ushort* __restrict__ BT,
                                               void* __restrict__ Cout,
                                               int N, int K, int nx) {
    __shared__ __attribute__((aligned(16))) ushort As[2][4][128][8];
    __shared__ __attribute__((aligned(16))) ushort Bs[2][4][128][8];
    const int tid = threadIdx.x;
    const int l = tid & 63, li = l & 15, lg = l >> 4;
    const int w = tid >> 6;
    const int wr = w >> 1, wc = w & 1;

    // XCD-aware bijective swizzle: consecutive swz-blocks share an XCD's L2
    const int lin = blockIdx.x;
    const int q = gridDim.x >> 3;
    const int swz = (lin & 7) * q + (lin >> 3);
    const int row0 = (swz / nx) * 128, col0 = (swz % nx) * 128;

    f32x4 acc[4][4];
#pragma unroll
    for (int i = 0; i < 4; ++i)
#pragma unroll
        for (int j = 0; j < 4; ++j) {
            acc[i][j][0] = 0.f; acc[i][j][1] = 0.f;
            acc[i][j][2] = 0.f; acc[i][j][3] = 0.f;
        }

    const int nk = K >> 5;

#define G_STAGE(buf, kk)                                                        \
    {                                                                           \
        int k0 = (kk) << 5;                                                     \
        _Pragma("unroll")                                                       \
        for (int i = 0; i < 2; ++i) {                                           \
            int id = w + i * 4;                                                 \
            int g = id >> 1, h = id & 1;                                        \
            gld16(A + (size_t)(row0 + h * 64 + l) * K + k0 + g * 8,             \
                  &As[buf][g][h * 64][0]);                                      \
            gld16(BT + (size_t)(col0 + h * 64 + l) * K + k0 + g * 8,            \
                  &Bs[buf][g][h * 64][0]);                                      \
        }                                                                       \
    }

    G_STAGE(0, 0);
    __syncthreads();
    int buf = 0;
    for (int kk = 0; kk < nk; ++kk) {
        if (kk + 1 < nk) G_STAGE(buf ^ 1, kk + 1);
        short8 af[4], bfr[4];
#pragma unroll
        for (int mt = 0; mt < 4; ++mt)
            af[mt] = *(const short8*)&As[buf][lg][wr * 64 + mt * 16 + li][0];
#pragma unroll
        for (int nt = 0; nt < 4; ++nt)
            bfr[nt] = *(const short8*)&Bs[buf][lg][wc * 64 + nt * 16 + li][0];
#pragma unroll
        for (int mt = 0; mt < 4; ++mt)
#pragma unroll
            for (int nt = 0; nt < 4; ++nt)
                acc[mt][nt] = __builtin_amdgcn_mfma_f32_16x16x32_bf16(
                    af[mt], bfr[nt], acc[mt][nt], 0, 0, 0);
        __syncthreads();
        buf ^= 1;
    }
#undef G_STAGE

    if (WRITE_BF16) {
        ushort* C = (ushort*)Cout;
#pragma unroll
        for (int mt = 0; mt < 4; ++mt)
#pragma unroll
            for (int r = 0; r < 4; ++r) {
                int rg = row0 + wr * 64 + mt * 16 + lg * 4 + r;
#pragma unroll
                for (int nt = 0; nt < 4; ++nt)
                    C[(size_t)rg * N + col0 + wc * 64 + nt * 16 + li] =
                        f2bf_u(acc[mt][nt][r]);
            }
    } else {
        float* C = (float*)Cout;
#pragma unroll
        for (int mt = 0; mt < 4; ++mt)
#pragma unroll
            for (int r = 0; r < 4; ++r) {
                int rg = row0 + wr * 64 + mt * 16 + lg * 4 + r;
#pragma unroll
                for (int nt = 0; nt < 4; ++nt)
                    C[(size_t)rg * N + col0 + wc * 64 + nt * 16 + li] =
                        acc[mt][nt][r];
            }
    }
}

// ---------------- flash attention, 2-phase pipelined, balanced pairing -------
// (round-9 kernel, measured 65.4us) Each block handles q-tiles {bx, 31-bx}.
// Q pre-scaled (SCL in Wq). Defer-max (THR=8, exact). V-pack via v_perm_b32.
__global__ __launch_bounds__(256) void attn_mfma(const ushort* __restrict__ qkv,
                                                 ushort* __restrict__ o) {
    __shared__ __attribute__((aligned(16))) char smem[40960];
    ushort (*Ks)[8][64][8] = (ushort (*)[8][64][8])smem;          // 2 x 8KB
    unsigned (*VtD)[2048]  = (unsigned (*)[2048])(smem + 16384);  // 2 x 8KB
    ushort (*Ps)[8][16][8] = (ushort (*)[8][16][8])(smem + 32768);// 8KB

    const int tid = threadIdx.x;
    const int l = tid & 63, li = l & 15, lg = l >> 4;
    const int w = tid >> 6;
    const int bx = blockIdx.x;                   // 0..15
    const int hq = blockIdx.y, b = blockIdx.z, hk = hq >> 2;

    const int kp = 2 * (tid & 31), d0v = (tid >> 5) * 8;
    const int gv = kp >> 3, prv = (kp & 7) >> 1;

    const ushort* base  = qkv + (size_t)b * Nseq * QKVW;
    const ushort* vbase = base + 1280 + hk * 64 + d0v;     // + row*QKVW
    const int qloc = w * 16 + li;                          // lane's q-row in tile

    for (int hseg = 0; hseg < 2; ++hseg) {
        const int qt = hseg ? (31 - bx) : bx;
        const int r0 = qt * 64;

        short8 q8[2];
#pragma unroll
        for (int c = 0; c < 2; ++c)
            q8[c] = *(const short8*)(base + (size_t)(r0 + qloc) * QKVW +
                                     hq * 64 + (c * 4 + lg) * 8);

#pragma unroll
        for (int i = 0; i < 2; ++i) {
            int g = w + i * 4;
            gld16(base + (size_t)l * QKVW + 1024 + hk * 64 + g * 8,
                  &Ks[0][g][0][0]);
        }
        short8 va = *(const short8*)(vbase + (size_t)kp * QKVW);
        short8 vb = *(const short8*)(vbase + (size_t)(kp + 1) * QKVW);
        __syncthreads();                  // K(0) in LDS; V(0) regs complete
        {
            S8U ua, ub; ua.s8 = va; ub.s8 = vb;
#pragma unroll
            for (int j = 0; j < 4; ++j) {
                VtD[0][gv * 256 + (((d0v + 2 * j) * 4 + prv) ^ (gv << 2))] =
                    __builtin_amdgcn_perm(ub.u[j], ua.u[j], 0x05040100u);
                VtD[0][gv * 256 + (((d0v + 2 * j + 1) * 4 + prv) ^ (gv << 2))] =
                    __builtin_amdgcn_perm(ub.u[j], ua.u[j], 0x07060302u);
            }
        }
        __syncthreads();                  // V(0) visible

        f32x4 oacc[4];
#pragma unroll
        for (int dt = 0; dt < 4; ++dt) {
            oacc[dt][0] = 0.f; oacc[dt][1] = 0.f;
            oacc[dt][2] = 0.f; oacc[dt][3] = 0.f;
        }
        float m = -INFINITY, lsum = 0.f;

        for (int t = 0; t <= qt; ++t) {
            const int cur = t & 1, nxt = cur ^ 1;
            const bool pre = (t < qt);
            short8 vna, vnb;
            if (pre) {                    // issue next tile's loads FIRST
                const int s1 = (t + 1) * 64;
#pragma unroll
                for (int i = 0; i < 2; ++i) {
                    int g = w + i * 4;
                    gld16(base + (size_t)(s1 + l) * QKVW + 1024 + hk * 64 + g * 8,
                          &Ks[nxt][g][0][0]);
                }
                const ushort* vr = vbase + (size_t)(s1 + kp) * QKVW;
                vna = *(const short8*)vr;
                vnb = *(const short8*)(vr + QKVW);
            }

            // S^T = K Q  (swapped: lane holds q-row li, keys kb*16+lg*4+r)
            f32x4 s[4];
#pragma unroll
            for (int kb = 0; kb < 4; ++kb) {
                s[kb][0] = 0.f; s[kb][1] = 0.f; s[kb][2] = 0.f; s[kb][3] = 0.f;
            }
#pragma unroll
            for (int c = 0; c < 2; ++c)
#pragma unroll
                for (int kb = 0; kb < 4; ++kb) {
                    short8 bk = *(const short8*)&Ks[cur][c * 4 + lg][kb * 16 + li][0];
                    s[kb] = __builtin_amdgcn_mfma_f32_16x16x32_bf16(bk, q8[c], s[kb], 0, 0, 0);
                }

            // causal mask (uniform branch; only diagonal tile partial)
            float p[16];
            const bool last = (t == qt);
#pragma unroll
            for (int kb = 0; kb < 4; ++kb)
#pragma unroll
                for (int r = 0; r < 4; ++r) {
                    float sv = s[kb][r];
                    if (last && (kb * 16 + lg * 4 + r > qloc)) sv = -INFINITY;
                    p[kb * 4 + r] = sv;
                }

            // row max via max tree + 2 cross-lg shuffles
            float mx = fmaxf(fmaxf(
                fmaxf(fmaxf(p[0], p[1]), fmaxf(p[2], p[3])),
                fmaxf(fmaxf(p[4], p[5]), fmaxf(p[6], p[7]))),
                fmaxf(fmaxf(fmaxf(p[8], p[9]), fmaxf(p[10], p[11])),
                      fmaxf(fmaxf(p[12], p[13]), fmaxf(p[14], p[15]))));
            mx = fmaxf(mx, __shfl_xor(mx, 16, 64));
            mx = fmaxf(mx, __shfl_xor(mx, 32, 64));

            // defer-max: only update offset/rescale when growth > 8 (exact)
            if (__any(mx - m > 8.0f)) {
                float mn = fmaxf(m, mx);
                float al = exp2f(m - mn);   // first tile: exp2(-inf)=0
                m = mn;
                lsum *= al;
                float alr[4];
#pragma unroll
                for (int r = 0; r < 4; ++r) alr[r] = __shfl(al, lg * 4 + r, 64);
#pragma unroll
                for (int dt = 0; dt < 4; ++dt)
#pragma unroll
                    for (int r = 0; r < 4; ++r) oacc[dt][r] *= alr[r];
            }

            float sum = 0.f;
#pragma unroll
            for (int i = 0; i < 16; ++i) {
                float e = exp2f(p[i] - m);
                p[i] = e;
                sum += e;
            }
            sum += __shfl_xor(sum, 16, 64);
            sum += __shfl_xor(sum, 32, 64);
            lsum += sum;

            // pack P -> LDS (b64 per kb)
#pragma unroll
            for (int kb = 0; kb < 4; ++kb) {
                unsigned lo = bfpk(p[kb * 4 + 0], p[kb * 4 + 1]);
                unsigned hi = bfpk(p[kb * 4 + 2], p[kb * 4 + 3]);
                *(unsigned long long*)&Ps[w][2 * kb + (lg >> 1)][li][(lg & 1) * 4] =
                    ((unsigned long long)hi << 32) | (unsigned long long)lo;
            }

            // write V(t+1) regs -> LDS (overlapped with softmax above)
            if (pre) {
                S8U ua, ub; ua.s8 = vna; ub.s8 = vnb;
#pragma unroll
                for (int j = 0; j < 4; ++j) {
                    VtD[nxt][gv * 256 + (((d0v + 2 * j) * 4 + prv) ^ (gv << 2))] =
                        __builtin_amdgcn_perm(ub.u[j], ua.u[j], 0x05040100u);
                    VtD[nxt][gv * 256 + (((d0v + 2 * j + 1) * 4 + prv) ^ (gv << 2))] =
                        __builtin_amdgcn_perm(ub.u[j], ua.u[j], 0x07060302u);
                }
            }

            // O += P V  (same-wave P; wave-ordered LDS)
#pragma unroll
            for (int c = 0; c < 2; ++c) {
                short8 pa = *(const short8*)&Ps[w][c * 4 + lg][li][0];
#pragma unroll
                for (int dt = 0; dt < 4; ++dt) {
                    int g = c * 4 + lg, d = dt * 16 + li;
                    short8 bv = *(const short8*)(&VtD[cur][g * 256 + ((d * 4) ^ (g << 2))]);
                    oacc[dt] = __builtin_amdgcn_mfma_f32_16x16x32_bf16(pa, bv, oacc[dt], 0, 0, 0);
                }
            }
            __syncthreads();   // drains K(t+1) gld16 + V writes; cur reads done
        }

        // epilogue: 1/l for q-row lg*4+r from lane lg*4+r
        float linv[4];
#pragma unroll
        for (int r = 0; r < 4; ++r) linv[r] = 1.0f / __shfl(lsum, lg * 4 + r, 64);
#pragma unroll
        for (int r = 0; r < 4; ++r) {
            int rg = b * Nseq + r0 + w * 16 + lg * 4 + r;
#pragma unroll
            for (int dt = 0; dt < 4; ++dt)
                o[(size_t)rg * Edim + hq * 64 + dt * 16 + li] =
                    f2bf_u(oacc[dt][r] * linv[r]);
        }
    }
}

// ---------------- launch ------------------------------------------------------
extern "C" void kernel_launch(void* const* d_in, const int* in_sizes, int n_in,
                              void* d_out, int out_size, void* d_ws, size_t ws_size,
                              hipStream_t stream) {
    const float* x  = (const float*)d_in[0];
    const float* Wq = (const float*)d_in[1];
    const float* Wk = (const float*)d_in[2];
    const float* Wv = (const float*)d_in[3];
    const float* Wo = (const float*)d_in[4];

    ushort* ws    = (ushort*)d_ws;
    ushort* xb    = ws;                          // 4096x1024
    ushort* WqkvT = xb + (size_t)ROWS * Edim;    // 1536x1024 (rows: WqT|WkT|WvT)
    ushort* WoT   = WqkvT + (size_t)QKVW * Edim; // 1024x1024
    ushort* qkv   = WoT + (size_t)Edim * Edim;   // 4096x1536 bf16
    ushort* at    = qkv + (size_t)ROWS * QKVW;   // 4096x1024 bf16

    prep<<<4608, 256, 0, stream>>>(x, Wq, Wk, Wv, Wo, xb, WqkvT, WoT);

    // QKV projection: 4096x1536x1024, grid 384 blocks (nx = 1536/128 = 12)
    gemm_bt<1><<<(QKVW / 128) * (ROWS / 128), 256, 0, stream>>>(
        xb, WqkvT, qkv, QKVW, Edim, QKVW / 128);

    attn_mfma<<<dim3(Nseq / 128, HQ, Bsz), 256, 0, stream>>>(qkv, at);

    // Output projection: 4096x1024x1024, grid 256 blocks (nx = 8)
    gemm_bt<0><<<(Edim / 128) * (ROWS / 128), 256, 0, stream>>>(
        at, WoT, d_out, Edim, Edim, Edim / 128);
}